// Round 11
// baseline (431.587 us; speedup 1.0000x reference)
//
#include <hip/hip_runtime.h>
#include <hip/hip_bf16.h>

#define B_ 32
#define N_ 1024
#define D_ 512
#define LN_EPS 1e-5f

using bf16 = __bf16;
using bf16x4 = __attribute__((ext_vector_type(4))) __bf16;
using bf16x8 = __attribute__((ext_vector_type(8))) __bf16;
using floatx4 = __attribute__((ext_vector_type(4))) float;

__device__ __forceinline__ void gld16(const bf16* gp, bf16* lp) {
  __builtin_amdgcn_global_load_lds(
      (const __attribute__((address_space(1))) void*)gp,
      (__attribute__((address_space(3))) void*)lp, 16, 0, 0);
}

// ---- fused pre-pass, no atomics / no memset ----
// blk < 512: deg partial col-sums + Abf cast. block (b, rc) owns ALL 1024
//   cols of rows [rc*64, rc*64+64): wave reads 1KB contiguous per row,
//   block streams 256KB contiguous. Partial sums -> deg_part[rc][b][1024].
// blk >= 512: fp32->bf16 transposed weight cast (W1, W2).
__global__ __launch_bounds__(256) void k_pre(const float* __restrict__ A,
                                             float* __restrict__ deg_part,
                                             bf16* __restrict__ Abf,
                                             const float* __restrict__ W1,
                                             bf16* __restrict__ W1t,
                                             const float* __restrict__ W2,
                                             bf16* __restrict__ W2t) {
  int blk = blockIdx.x;
  int t = threadIdx.x;
  if (blk < 512) {
    int b = blk >> 4;
    int rc = blk & 15;
    int r0 = rc * 64;
    const float* p = A + (size_t)b * N_ * N_ + (size_t)r0 * N_ + t * 4;
    bf16* op = Abf + (size_t)b * N_ * N_ + (size_t)r0 * N_ + t * 4;
    float4 acc = {0.f, 0.f, 0.f, 0.f};
    #pragma unroll 4
    for (int i = 0; i < 64; ++i) {
      float4 v = *(const float4*)(p + (size_t)i * N_);
      acc.x += v.x; acc.y += v.y; acc.z += v.z; acc.w += v.w;
      bf16x4 o = {(bf16)v.x, (bf16)v.y, (bf16)v.z, (bf16)v.w};
      *(bf16x4*)(op + (size_t)i * N_) = o;
    }
    *(float4*)(deg_part + ((size_t)rc * B_ + b) * N_ + t * 4) = acc;
  } else {
    __shared__ float tile[64][65];
    blk -= 512;
    const float* in; bf16* outp; int R, C, c0, r0;
    if (blk < 128) {
      in = W1; outp = W1t; R = N_; C = D_;
      c0 = (blk & 7) * 64; r0 = (blk >> 3) * 64;
    } else {
      blk -= 128;
      in = W2; outp = W2t; R = D_; C = D_;
      c0 = (blk & 7) * 64; r0 = (blk >> 3) * 64;
    }
    #pragma unroll
    for (int cc = 0; cc < 4; ++cc) {
      int idx = cc * 256 + t;
      int r = idx >> 4, c4 = (idx & 15) << 2;
      const float4 v = *(const float4*)(in + (size_t)(r0 + r) * C + c0 + c4);
      tile[r][c4 + 0] = v.x; tile[r][c4 + 1] = v.y;
      tile[r][c4 + 2] = v.z; tile[r][c4 + 3] = v.w;
    }
    __syncthreads();
    #pragma unroll
    for (int cc = 0; cc < 4; ++cc) {
      int idx = cc * 256 + t;
      int c = idx >> 4, r4 = (idx & 15) << 2;
      bf16* dst = outp + (size_t)(c0 + c) * R + r0 + r4;
      #pragma unroll
      for (int e = 0; e < 4; ++e) dst[e] = (bf16)tile[r4 + e][c];
    }
  }
}

// ------------- build Anbf = transpose(Abf) * rsqrt(deg_i) * rsqrt(deg_j) -------------
// deg comes as 16 row-chunk partials (summed here); bf16x8 both sides.
__global__ __launch_bounds__(256) void k_build(const bf16* __restrict__ Abf,
                                               const float* __restrict__ deg_part,
                                               bf16* __restrict__ Anbf) {
  __shared__ float tile[64][65];
  __shared__ float disI[64], disJ[64];
  int b = blockIdx.z;
  int i0 = blockIdx.x * 64;   // i range (cols of A read, rows of An)
  int j0 = blockIdx.y * 64;   // j range (rows of A read)
  int t = threadIdx.x;
  const bf16* Ab = Abf + (size_t)b * N_ * N_;
  bf16* Anb = Anbf + (size_t)b * N_ * N_;
  if (t < 64) {
    float v = 0.f;
    #pragma unroll
    for (int rc = 0; rc < 16; ++rc)
      v += deg_part[((size_t)rc * B_ + b) * N_ + i0 + t];
    disI[t] = v > 0.f ? rsqrtf(v) : 0.f;
  } else if (t < 128) {
    float v = 0.f;
    #pragma unroll
    for (int rc = 0; rc < 16; ++rc)
      v += deg_part[((size_t)rc * B_ + b) * N_ + j0 + (t - 64)];
    disJ[t - 64] = v > 0.f ? rsqrtf(v) : 0.f;
  }
  #pragma unroll
  for (int cc = 0; cc < 2; ++cc) {
    int idx = cc * 256 + t;         // 0..511
    int r = idx >> 3;               // 0..63 (row j offset)
    int c8 = (idx & 7) << 3;        // 0..56
    bf16x8 v = *(const bf16x8*)(Ab + (size_t)(j0 + r) * N_ + i0 + c8);
    #pragma unroll
    for (int e = 0; e < 8; ++e) tile[r][c8 + e] = (float)v[e];
  }
  __syncthreads();
  #pragma unroll
  for (int cc = 0; cc < 2; ++cc) {
    int idx = cc * 256 + t;
    int ii = idx >> 3;              // 0..63 (out row offset)
    int jj8 = (idx & 7) << 3;       // 0..56
    float di = disI[ii];
    bf16x8 o;
    #pragma unroll
    for (int e = 0; e < 8; ++e)
      o[e] = (bf16)(tile[jj8 + e][ii] * di * disJ[jj8 + e]);
    *(bf16x8*)(Anb + (size_t)(i0 + ii) * N_ + j0 + jj8) = o;
  }
}

// --------- 8-phase 256x256 MFMA GEMM (unchanged anchor) ----------
template <bool BIAS, bool RELU>
__global__ __launch_bounds__(512, 2) void k_gemm8(
    const bf16* __restrict__ Abase, size_t strideA,
    const bf16* __restrict__ Btbase, size_t strideBt,
    bf16* __restrict__ Cbase, size_t strideC,
    const float* __restrict__ bias, int Nn, int K) {
  __shared__ __align__(16) bf16 smem[65536];   // 128KB: sA=smem, sB=smem+32768
  bf16* sAp = smem;
  bf16* sBp = smem + 32768;

  int nxy = gridDim.x * gridDim.y;
  int L = blockIdx.z * nxy + blockIdx.y * gridDim.x + blockIdx.x;
  int b = (L & 7) + 8 * (L / (nxy * 8));
  int inner = (L >> 3) % nxy;
  int n0 = (inner % gridDim.x) * 256;
  int m0 = (inner / gridDim.x) * 256;
  const bf16* A = Abase + (size_t)b * strideA;
  const bf16* Bt = Btbase + (size_t)b * strideBt;
  int t = threadIdx.x;
  int lane = t & 63;
  int wid = t >> 6;
  int wm = wid >> 2, wn = wid & 3;     // wave tile 128x64 at (wm*128, wn*64)
  int l16 = lane & 15, q = lane >> 4;
  int xorb = l16 & 7;
  int ck0 = ((q ^ xorb) << 3);
  int ck1 = (((q + 4) ^ xorb) << 3);
  int r0 = t >> 3;
  int csrc = (((t & 7) ^ (r0 & 7)) << 3);
  const bf16* ag = A + (size_t)(m0 + r0) * K + csrc;
  const bf16* bg = Bt + (size_t)(n0 + ((r0 >> 5) << 6) + (r0 & 31)) * K + csrc;
  bf16* al = sAp + (size_t)t * 8;
  bf16* bl = sBp + (size_t)t * 8;

#define STAGE_A(bf_, hf_, kt_)                                                 \
  { gld16(ag + (size_t)((hf_) * 64) * K + (kt_),                               \
          al + (bf_) * 16384 + (hf_) * 8192);                                  \
    gld16(ag + (size_t)(128 + (hf_) * 64) * K + (kt_),                         \
          al + (bf_) * 16384 + (hf_) * 8192 + 4096); }
#define STAGE_B(bf_, hf_, kt_)                                                 \
  { gld16(bg + (size_t)((hf_) * 32) * K + (kt_),                               \
          bl + (bf_) * 16384 + (hf_) * 8192);                                  \
    gld16(bg + (size_t)(128 + (hf_) * 32) * K + (kt_),                         \
          bl + (bf_) * 16384 + (hf_) * 8192 + 4096); }

  floatx4 acc[8][4];
  #pragma unroll
  for (int i = 0; i < 8; ++i)
    #pragma unroll
    for (int j = 0; j < 4; ++j) acc[i][j] = (floatx4){0.f, 0.f, 0.f, 0.f};

  bf16x8 a[4][2];
  bf16x8 bq[4][2];
  const bf16* arow = sAp + (wm * 64 + l16) * 64;
  const bf16* brow = sBp + (wn * 32 + l16) * 64;

#define RD_A(bf_, mq_)                                                         \
  _Pragma("unroll") for (int i = 0; i < 4; ++i) {                              \
    a[i][0] = *(const bf16x8*)(arow + (bf_) * 16384 + (mq_) * 8192 +           \
                               i * 1024 + ck0);                                \
    a[i][1] = *(const bf16x8*)(arow + (bf_) * 16384 + (mq_) * 8192 +           \
                               i * 1024 + ck1);                                \
  }
#define RD_B(bf_, nq_)                                                         \
  _Pragma("unroll") for (int j = 0; j < 2; ++j) {                              \
    bq[(nq_) * 2 + j][0] = *(const bf16x8*)(brow + (bf_) * 16384 +             \
                                            (nq_) * 8192 + j * 1024 + ck0);    \
    bq[(nq_) * 2 + j][1] = *(const bf16x8*)(brow + (bf_) * 16384 +             \
                                            (nq_) * 8192 + j * 1024 + ck1);    \
  }
#define MFMA_Q(mq_, nq_)                                                       \
  _Pragma("unroll") for (int i = 0; i < 4; ++i)                                \
    _Pragma("unroll") for (int j = 0; j < 2; ++j) {                            \
      acc[(mq_) * 4 + i][(nq_) * 2 + j] =                                      \
          __builtin_amdgcn_mfma_f32_16x16x32_bf16(                             \
              a[i][0], bq[(nq_) * 2 + j][0],                                   \
              acc[(mq_) * 4 + i][(nq_) * 2 + j], 0, 0, 0);                     \
      acc[(mq_) * 4 + i][(nq_) * 2 + j] =                                      \
          __builtin_amdgcn_mfma_f32_16x16x32_bf16(                             \
              a[i][1], bq[(nq_) * 2 + j][1],                                   \
              acc[(mq_) * 4 + i][(nq_) * 2 + j], 0, 0, 0);                     \
    }
#define BARRIER __builtin_amdgcn_s_barrier()
#define LGKM0                                                                  \
  do {                                                                         \
    asm volatile("s_waitcnt lgkmcnt(0)" ::: "memory");                         \
    __builtin_amdgcn_sched_barrier(0);                                         \
  } while (0)
#define VMCNT(n_) asm volatile("s_waitcnt vmcnt(" #n_ ")" ::: "memory")

  // prologue: tile0 complete (buf0) + tile1's A0,B0 (buf1); 12 loads/thread
  STAGE_A(0, 0, 0); STAGE_B(0, 0, 0); STAGE_A(0, 1, 0); STAGE_B(0, 1, 0);
  STAGE_A(1, 0, 64); STAGE_B(1, 0, 64);
  VMCNT(4);
  BARRIER;
  int NI = K >> 7;   // 2 K-tiles per iteration
  for (int it = 0; it < NI; ++it) {
    int kb = it << 7;
    int k1 = kb + 64;
    int k2 = kb + 128; bool p2 = k2 < K;
    int k3 = kb + 192; bool p3 = k3 < K;
    bool lastit = (it == NI - 1);
    // ph1: buf0 Q(m0,n0)
    RD_A(0, 0); RD_B(0, 0);
    STAGE_A(1, 1, k1);
    BARRIER; LGKM0;
    __builtin_amdgcn_s_setprio(1); MFMA_Q(0, 0); __builtin_amdgcn_s_setprio(0);
    BARRIER;
    // ph2: buf0 Q(m0,n1)
    RD_B(0, 1);
    STAGE_B(1, 1, k1);
    BARRIER; LGKM0;
    __builtin_amdgcn_s_setprio(1); MFMA_Q(0, 1); __builtin_amdgcn_s_setprio(0);
    BARRIER;
    // ph3: buf0 Q(m1,n0)
    RD_A(0, 1);
    if (p2) STAGE_A(0, 0, k2);
    BARRIER; LGKM0;
    __builtin_amdgcn_s_setprio(1); MFMA_Q(1, 0); __builtin_amdgcn_s_setprio(0);
    BARRIER;
    // ph4: buf0 Q(m1,n1) + vmcnt (guards ph5-8 reads of buf1)
    if (p2) STAGE_B(0, 0, k2);
    if (lastit) { VMCNT(0); } else { VMCNT(4); }
    BARRIER; LGKM0;
    __builtin_amdgcn_s_setprio(1); MFMA_Q(1, 1); __builtin_amdgcn_s_setprio(0);
    BARRIER;
    // ph5: buf1 Q(m0,n0)
    RD_A(1, 0); RD_B(1, 0);
    if (p2) STAGE_A(0, 1, k2);
    BARRIER; LGKM0;
    __builtin_amdgcn_s_setprio(1); MFMA_Q(0, 0); __builtin_amdgcn_s_setprio(0);
    BARRIER;
    // ph6: buf1 Q(m0,n1)
    RD_B(1, 1);
    if (p2) STAGE_B(0, 1, k2);
    BARRIER; LGKM0;
    __builtin_amdgcn_s_setprio(1); MFMA_Q(0, 1); __builtin_amdgcn_s_setprio(0);
    BARRIER;
    // ph7: buf1 Q(m1,n0)
    RD_A(1, 1);
    if (p3) STAGE_A(1, 0, k3);
    BARRIER; LGKM0;
    __builtin_amdgcn_s_setprio(1); MFMA_Q(1, 0); __builtin_amdgcn_s_setprio(0);
    BARRIER;
    // ph8: buf1 Q(m1,n1) + vmcnt (guards next ph1-4 reads of buf0)
    if (p3) STAGE_B(1, 0, k3);
    if (lastit) { VMCNT(0); } else { VMCNT(4); }
    BARRIER; LGKM0;
    __builtin_amdgcn_s_setprio(1); MFMA_Q(1, 1); __builtin_amdgcn_s_setprio(0);
    BARRIER;
  }

  // ---- coalesced epilogue: stage C half-tile through LDS, store bf16x8 ----
  bf16* C = Cbase + (size_t)b * strideC;
  #pragma unroll
  for (int h = 0; h < 2; ++h) {
    BARRIER;   // WAR vs K-loop LDS reads (h=0) / prev half's LDS reads (h=1)
    if (wm == h) {
      #pragma unroll
      for (int fm = 0; fm < 8; ++fm)
        #pragma unroll
        for (int fn = 0; fn < 4; ++fn)
          #pragma unroll
          for (int r = 0; r < 4; ++r) {
            float v = acc[fm][fn][r];
            if (BIAS) v += bias[n0 + wn * 64 + fn * 16 + l16];
            if (RELU) v = v > 0.f ? v : 0.f;
            smem[(fm * 16 + q * 4 + r) * 264 + wn * 64 + fn * 16 + l16] =
                (bf16)v;
          }
    }
    BARRIER;
    #pragma unroll
    for (int i = 0; i < 8; ++i) {
      int idx = i * 512 + t;            // 0..4095 chunks of 8 elems
      int row = idx >> 5;               // 0..127
      int c8 = (idx & 31) << 3;         // 0..248
      bf16x8 vv = *(const bf16x8*)(smem + row * 264 + c8);
      *(bf16x8*)(C + (size_t)(m0 + h * 128 + row) * Nn + n0 + c8) = vv;
    }
  }
#undef STAGE_A
#undef STAGE_B
#undef RD_A
#undef RD_B
#undef MFMA_Q
#undef BARRIER
#undef LGKM0
#undef VMCNT
}

// ------- LayerNorm over D + mean-pool over N: per-block partials (no atomics) -------
__global__ __launch_bounds__(256) void k_lnpool(const bf16* __restrict__ H2,
                                                const float* __restrict__ g,
                                                const float* __restrict__ be,
                                                float* __restrict__ zp_part) {
  int b = blockIdx.y;
  int rx = blockIdx.x;
  int r0 = rx * 64;
  int t = threadIdx.x, lane = t & 63, w = t >> 6;
  float ge[8], bee[8];
  #pragma unroll
  for (int e = 0; e < 8; ++e) { ge[e] = g[lane * 8 + e]; bee[e] = be[lane * 8 + e]; }
  float acc[8] = {0, 0, 0, 0, 0, 0, 0, 0};
  for (int rr = 0; rr < 16; ++rr) {
    int row = r0 + w * 16 + rr;
    const bf16* p = H2 + ((size_t)b * N_ + row) * D_ + lane * 8;
    bf16x8 hv = *(const bf16x8*)p;
    float x[8];
    float s = 0.f;
    #pragma unroll
    for (int e = 0; e < 8; ++e) { x[e] = (float)hv[e]; s += x[e]; }
    #pragma unroll
    for (int off = 32; off; off >>= 1) s += __shfl_xor(s, off);
    float mu = s * (1.f / 512.f);
    float ss = 0.f;
    #pragma unroll
    for (int e = 0; e < 8; ++e) { float d = x[e] - mu; ss += d * d; }
    #pragma unroll
    for (int off = 32; off; off >>= 1) ss += __shfl_xor(ss, off);
    float rs = rsqrtf(ss * (1.f / 512.f) + LN_EPS);
    #pragma unroll
    for (int e = 0; e < 8; ++e) acc[e] += (x[e] - mu) * rs * ge[e] + bee[e];
  }
  __shared__ float part[4][512];
  #pragma unroll
  for (int e = 0; e < 8; ++e) part[w][lane * 8 + e] = acc[e];
  __syncthreads();
  #pragma unroll
  for (int k = 0; k < 2; ++k) {
    int d = t + k * 256;
    float s4 = part[0][d] + part[1][d] + part[2][d] + part[3][d];
    zp_part[((size_t)rx * B_ + b) * D_ + d] = s4;
  }
}

// ---------------- classifier head (reduces zp partials) ----------------
__global__ __launch_bounds__(128) void k_cls(
    const float* __restrict__ zp_part,
    const float* __restrict__ Wc1, const float* __restrict__ bc1,
    const float* __restrict__ g1, const float* __restrict__ t1,
    const float* __restrict__ Wc2, const float* __restrict__ bc2,
    const float* __restrict__ g2, const float* __restrict__ t2,
    const float* __restrict__ Wc3, const float* __restrict__ bc3,
    float* __restrict__ out) {
  __shared__ float z[512];
  __shared__ float c1s[128];
  __shared__ float c2s[64];
  __shared__ float red[128];
  int b = blockIdx.x, t = threadIdx.x;
  #pragma unroll
  for (int k = 0; k < 4; ++k) {
    int d = t + k * 128;
    float s = 0.f;
    #pragma unroll
    for (int rx = 0; rx < 16; ++rx)
      s += zp_part[((size_t)rx * B_ + b) * D_ + d];
    float v = s * (1.f / 1024.f);
    z[d] = v;
    out[128 + b * 512 + d] = v;   // z_pooled output region
  }
  __syncthreads();
  float y = bc1[t];
  for (int d = 0; d < 512; ++d) y += z[d] * Wc1[d * 128 + t];
  red[t] = y;
  __syncthreads();
  float mu = 0.f;
  for (int k = 0; k < 128; ++k) mu += red[k];
  mu *= (1.f / 128.f);
  float var = 0.f;
  for (int k = 0; k < 128; ++k) { float dd = red[k] - mu; var += dd * dd; }
  var *= (1.f / 128.f);
  float c = (y - mu) * rsqrtf(var + LN_EPS) * g1[t] + t1[t];
  c1s[t] = c > 0.f ? c : 0.f;
  __syncthreads();
  if (t < 64) {
    float y2 = bc2[t];
    for (int k = 0; k < 128; ++k) y2 += c1s[k] * Wc2[k * 64 + t];
    red[t] = y2;
  }
  __syncthreads();
  if (t < 64) {
    float mu2 = 0.f;
    for (int k = 0; k < 64; ++k) mu2 += red[k];
    mu2 *= (1.f / 64.f);
    float v2 = 0.f;
    for (int k = 0; k < 64; ++k) { float dd = red[k] - mu2; v2 += dd * dd; }
    v2 *= (1.f / 64.f);
    float cc = (red[t] - mu2) * rsqrtf(v2 + LN_EPS) * g2[t] + t2[t];
    c2s[t] = cc > 0.f ? cc : 0.f;
  }
  __syncthreads();
  if (t < 4) {
    float y3 = bc3[t];
    for (int k = 0; k < 64; ++k) y3 += c2s[k] * Wc3[k * 4 + t];
    out[b * 4 + t] = y3;
  }
}

extern "C" void kernel_launch(void* const* d_in, const int* in_sizes, int n_in,
                              void* d_out, int out_size, void* d_ws, size_t ws_size,
                              hipStream_t stream) {
  const float* A   = (const float*)d_in[0];
  const float* W1  = (const float*)d_in[1];
  const float* b1  = (const float*)d_in[2];
  const float* W2  = (const float*)d_in[3];
  const float* b2  = (const float*)d_in[4];
  const float* lng = (const float*)d_in[5];
  const float* lnb = (const float*)d_in[6];
  const float* Wc1 = (const float*)d_in[7];
  const float* bc1 = (const float*)d_in[8];
  const float* g1  = (const float*)d_in[9];
  const float* t1  = (const float*)d_in[10];
  const float* Wc2 = (const float*)d_in[11];
  const float* bc2 = (const float*)d_in[12];
  const float* g2  = (const float*)d_in[13];
  const float* t2  = (const float*)d_in[14];
  const float* Wc3 = (const float*)d_in[15];
  const float* bc3 = (const float*)d_in[16];
  float* out = (float*)d_out;

  char* ws = (char*)d_ws;
  size_t off = 0;
  auto alloc = [&](size_t bytes) {
    char* p = ws + off;
    off += (bytes + 255) & ~(size_t)255;
    return p;
  };
  float* deg_part = (float*)alloc((size_t)16 * B_ * N_ * 4);  // 2 MB partials
  float* zp_part  = (float*)alloc((size_t)16 * B_ * D_ * 4);  // 1 MB partials
  bf16* Anbf  = (bf16*)alloc((size_t)B_ * N_ * N_ * 2);       // 64 MB
  bf16* W1t   = (bf16*)alloc((size_t)D_ * N_ * 2);            // [512 x 1024]
  bf16* W2t   = (bf16*)alloc((size_t)D_ * D_ * 2);            // [512 x 512]
  bf16* T12t  = (bf16*)alloc((size_t)B_ * D_ * N_ * 2);       // T1t then T2t
  bf16* H1    = (bf16*)alloc((size_t)B_ * N_ * D_ * 2);       // [b][1024][512]
  bf16* Abf   = (bf16*)alloc((size_t)B_ * N_ * N_ * 2);       // later reused as H2
  bf16* H2    = Abf;                                           // Abf dead after GEMM1

  // no memset needed: deg_part and zp_part are fully written before read

  k_pre<<<704, 256, 0, stream>>>(A, deg_part, Abf, W1, W1t, W2, W2t);
  k_build<<<dim3(16, 16, B_), 256, 0, stream>>>(Abf, deg_part, Anbf);

  // G1: T1t[512,1024] = W1t @ Abf^T
  k_gemm8<false, false><<<dim3(4, 2, B_), 512, 0, stream>>>(
      W1t, 0, Abf, (size_t)N_ * N_, T12t, (size_t)D_ * N_, nullptr, N_, N_);
  // G2: H1 = relu(An @ T1t^T + b1)
  k_gemm8<true, true><<<dim3(2, 4, B_), 512, 0, stream>>>(
      Anbf, (size_t)N_ * N_, T12t, (size_t)D_ * N_, H1, (size_t)N_ * D_, b1, D_, N_);
  // G3: T2t[512,1024] = W2t @ H1^T
  k_gemm8<false, false><<<dim3(4, 2, B_), 512, 0, stream>>>(
      W2t, 0, H1, (size_t)N_ * D_, T12t, (size_t)D_ * N_, nullptr, N_, D_);
  // G4: H2 = An @ T2t^T + b2
  k_gemm8<true, false><<<dim3(2, 4, B_), 512, 0, stream>>>(
      Anbf, (size_t)N_ * N_, T12t, (size_t)D_ * N_, H2, (size_t)N_ * D_, b2, D_, N_);

  k_lnpool<<<dim3(16, B_), 256, 0, stream>>>(H2, lng, lnb, zp_part);
  k_cls<<<B_, 128, 0, stream>>>(zp_part, Wc1, bc1, g1, t1, Wc2, bc2, g2, t2,
                                Wc3, bc3, out);
}

// Round 12
// 418.385 us; speedup vs baseline: 1.0316x; 1.0316x over previous
//
#include <hip/hip_runtime.h>
#include <hip/hip_bf16.h>

#define B_ 32
#define N_ 1024
#define D_ 512
#define LN_EPS 1e-5f

using bf16 = __bf16;
using bf16x4 = __attribute__((ext_vector_type(4))) __bf16;
using bf16x8 = __attribute__((ext_vector_type(8))) __bf16;
using floatx4 = __attribute__((ext_vector_type(4))) float;

__device__ __forceinline__ void gld16(const bf16* gp, bf16* lp) {
  __builtin_amdgcn_global_load_lds(
      (const __attribute__((address_space(1))) void*)gp,
      (__attribute__((address_space(3))) void*)lp, 16, 0, 0);
}

// ---- fused pre-pass, no atomics / no memset (r11) ----
__global__ __launch_bounds__(256) void k_pre(const float* __restrict__ A,
                                             float* __restrict__ deg_part,
                                             bf16* __restrict__ Abf,
                                             const float* __restrict__ W1,
                                             bf16* __restrict__ W1t,
                                             const float* __restrict__ W2,
                                             bf16* __restrict__ W2t) {
  int blk = blockIdx.x;
  int t = threadIdx.x;
  if (blk < 512) {
    int b = blk >> 4;
    int rc = blk & 15;
    int r0 = rc * 64;
    const float* p = A + (size_t)b * N_ * N_ + (size_t)r0 * N_ + t * 4;
    bf16* op = Abf + (size_t)b * N_ * N_ + (size_t)r0 * N_ + t * 4;
    float4 acc = {0.f, 0.f, 0.f, 0.f};
    #pragma unroll 4
    for (int i = 0; i < 64; ++i) {
      float4 v = *(const float4*)(p + (size_t)i * N_);
      acc.x += v.x; acc.y += v.y; acc.z += v.z; acc.w += v.w;
      bf16x4 o = {(bf16)v.x, (bf16)v.y, (bf16)v.z, (bf16)v.w};
      *(bf16x4*)(op + (size_t)i * N_) = o;
    }
    *(float4*)(deg_part + ((size_t)rc * B_ + b) * N_ + t * 4) = acc;
  } else {
    __shared__ float tile[64][65];
    blk -= 512;
    const float* in; bf16* outp; int R, C, c0, r0;
    if (blk < 128) {
      in = W1; outp = W1t; R = N_; C = D_;
      c0 = (blk & 7) * 64; r0 = (blk >> 3) * 64;
    } else {
      blk -= 128;
      in = W2; outp = W2t; R = D_; C = D_;
      c0 = (blk & 7) * 64; r0 = (blk >> 3) * 64;
    }
    #pragma unroll
    for (int cc = 0; cc < 4; ++cc) {
      int idx = cc * 256 + t;
      int r = idx >> 4, c4 = (idx & 15) << 2;
      const float4 v = *(const float4*)(in + (size_t)(r0 + r) * C + c0 + c4);
      tile[r][c4 + 0] = v.x; tile[r][c4 + 1] = v.y;
      tile[r][c4 + 2] = v.z; tile[r][c4 + 3] = v.w;
    }
    __syncthreads();
    #pragma unroll
    for (int cc = 0; cc < 4; ++cc) {
      int idx = cc * 256 + t;
      int c = idx >> 4, r4 = (idx & 15) << 2;
      bf16* dst = outp + (size_t)(c0 + c) * R + r0 + r4;
      #pragma unroll
      for (int e = 0; e < 4; ++e) dst[e] = (bf16)tile[r4 + e][c];
    }
  }
}

// ------------- build Anbf = transpose(Abf) * rsqrt(deg_i) * rsqrt(deg_j) -------------
__global__ __launch_bounds__(256) void k_build(const bf16* __restrict__ Abf,
                                               const float* __restrict__ deg_part,
                                               bf16* __restrict__ Anbf) {
  __shared__ float tile[64][65];
  __shared__ float disI[64], disJ[64];
  int b = blockIdx.z;
  int i0 = blockIdx.x * 64;
  int j0 = blockIdx.y * 64;
  int t = threadIdx.x;
  const bf16* Ab = Abf + (size_t)b * N_ * N_;
  bf16* Anb = Anbf + (size_t)b * N_ * N_;
  if (t < 64) {
    float v = 0.f;
    #pragma unroll
    for (int rc = 0; rc < 16; ++rc)
      v += deg_part[((size_t)rc * B_ + b) * N_ + i0 + t];
    disI[t] = v > 0.f ? rsqrtf(v) : 0.f;
  } else if (t < 128) {
    float v = 0.f;
    #pragma unroll
    for (int rc = 0; rc < 16; ++rc)
      v += deg_part[((size_t)rc * B_ + b) * N_ + j0 + (t - 64)];
    disJ[t - 64] = v > 0.f ? rsqrtf(v) : 0.f;
  }
  #pragma unroll
  for (int cc = 0; cc < 2; ++cc) {
    int idx = cc * 256 + t;
    int r = idx >> 3;
    int c8 = (idx & 7) << 3;
    bf16x8 v = *(const bf16x8*)(Ab + (size_t)(j0 + r) * N_ + i0 + c8);
    #pragma unroll
    for (int e = 0; e < 8; ++e) tile[r][c8 + e] = (float)v[e];
  }
  __syncthreads();
  #pragma unroll
  for (int cc = 0; cc < 2; ++cc) {
    int idx = cc * 256 + t;
    int ii = idx >> 3;
    int jj8 = (idx & 7) << 3;
    float di = disI[ii];
    bf16x8 o;
    #pragma unroll
    for (int e = 0; e < 8; ++e)
      o[e] = (bf16)(tile[jj8 + e][ii] * di * disJ[jj8 + e]);
    *(bf16x8*)(Anb + (size_t)(i0 + ii) * N_ + j0 + jj8) = o;
  }
}

// --------- MFMA GEMM: C[M,Nn] = A[M,K] @ Bt[Nn,K]^T (r0 structure) ----------
// 128x256 block tile, 4 waves each 64x128, BK=64, two-barrier K-loop,
// XOR-swizzled LDS, XCD-aware block swizzle, 48KB LDS, 2 blocks/CU.
// r12: LDS-staged coalesced C epilogue (fixes 2.25x write amplification
// measured in round 6) in two 64x256 halves (33.8KB, reuses the 48KB).
template <bool BIAS, bool RELU>
__global__ __launch_bounds__(256, 2) void k_gemm(
    const bf16* __restrict__ Abase, size_t strideA,
    const bf16* __restrict__ Btbase, size_t strideBt,
    bf16* __restrict__ Cbase, size_t strideC,
    const float* __restrict__ bias, int Nn, int K) {
  __shared__ __align__(16) bf16 smem[24576];   // 48KB: sA | sB
  bf16* sA = smem;           // 128*64
  bf16* sB = smem + 8192;    // 256*64
  // XCD swizzle: batch b's blocks all land on XCD b%8
  int nxy = gridDim.x * gridDim.y;            // blocks per batch (16 here)
  int L = blockIdx.z * nxy + blockIdx.y * gridDim.x + blockIdx.x;
  int b = (L & 7) + 8 * (L / (nxy * 8));
  int inner = (L >> 3) % nxy;
  int n0 = (inner % gridDim.x) * 256;
  int m0 = (inner / gridDim.x) * 128;

  const bf16* A = Abase + (size_t)b * strideA;
  const bf16* Bt = Btbase + (size_t)b * strideBt;
  int t = threadIdx.x;
  int lane = t & 63, wid = t >> 6;
  int wm = (wid >> 1) * 64, wn = (wid & 1) * 128;
  int l16 = lane & 15, q = lane >> 4;

  // staging: wave wid fills A rows [wid*32, +32) and B rows [wid*64, +64).
  // slot l of each 8-row window holds chunk (l&7)^(l>>3) of row l>>3.
  int rowoff = lane >> 3;                 // 0..7
  int schunk = (lane & 7) ^ rowoff;       // swizzled source chunk
  const bf16* agp = A + (size_t)(m0 + wid * 32 + rowoff) * K + schunk * 8;
  const bf16* bgp = Bt + (size_t)(n0 + wid * 64 + rowoff) * K + schunk * 8;
  bf16* alp = &sA[wid * 2048 + lane * 8];
  bf16* blp = &sB[wid * 4096 + lane * 8];

  int xorb = l16 & 7;

  floatx4 acc[4][8];
  #pragma unroll
  for (int i = 0; i < 4; ++i)
    #pragma unroll
    for (int j = 0; j < 8; ++j) acc[i][j] = (floatx4){0.f, 0.f, 0.f, 0.f};

  for (int kt = 0; kt < K; kt += 64) {
    #pragma unroll
    for (int s = 0; s < 4; ++s)
      gld16(agp + (size_t)s * 8 * K + kt, alp + s * 512);
    #pragma unroll
    for (int s = 0; s < 8; ++s)
      gld16(bgp + (size_t)s * 8 * K + kt, blp + s * 512);
    __syncthreads();
    #pragma unroll
    for (int h = 0; h < 2; ++h) {
      int cko = ((q + 4 * h) ^ xorb) * 8;
      bf16x8 af[4], bfr[8];
      #pragma unroll
      for (int mt = 0; mt < 4; ++mt)
        af[mt] = *(const bf16x8*)(&sA[(wm + mt * 16 + l16) * 64 + cko]);
      #pragma unroll
      for (int nt = 0; nt < 8; ++nt)
        bfr[nt] = *(const bf16x8*)(&sB[(wn + nt * 16 + l16) * 64 + cko]);
      #pragma unroll
      for (int mt = 0; mt < 4; ++mt)
        #pragma unroll
        for (int nt = 0; nt < 8; ++nt)
          acc[mt][nt] = __builtin_amdgcn_mfma_f32_16x16x32_bf16(
              af[mt], bfr[nt], acc[mt][nt], 0, 0, 0);
    }
    __syncthreads();
  }

  // ---- coalesced epilogue: two 64x256 halves through LDS, bf16x8 stores ----
  // half h = rows [h*64, h*64+64) of the tile, produced by waves wid>>1 == h.
  bf16* C = Cbase + (size_t)b * strideC;
  #pragma unroll
  for (int h = 0; h < 2; ++h) {
    if ((wid >> 1) == h) {
      #pragma unroll
      for (int mt = 0; mt < 4; ++mt)
        #pragma unroll
        for (int nt = 0; nt < 8; ++nt)
          #pragma unroll
          for (int r = 0; r < 4; ++r) {
            float v = acc[mt][nt][r];
            int col = wn + nt * 16 + l16;       // 0..255 in tile
            if (BIAS) v += bias[n0 + col];
            if (RELU) v = v > 0.f ? v : 0.f;
            smem[(mt * 16 + q * 4 + r) * 264 + col] = (bf16)v;
          }
    }
    __syncthreads();
    #pragma unroll
    for (int i = 0; i < 8; ++i) {
      int idx = i * 256 + t;              // 0..2047 chunks of 8 elems
      int row = idx >> 5;                 // 0..63
      int c8 = (idx & 31) << 3;           // 0..248
      bf16x8 vv = *(const bf16x8*)(smem + row * 264 + c8);
      *(bf16x8*)(C + (size_t)(m0 + h * 64 + row) * Nn + n0 + c8) = vv;
    }
    if (h == 0) __syncthreads();          // WAR before h=1 writes
  }
}

// ------- LayerNorm over D + mean-pool over N: per-block partials (no atomics) -------
__global__ __launch_bounds__(256) void k_lnpool(const bf16* __restrict__ H2,
                                                const float* __restrict__ g,
                                                const float* __restrict__ be,
                                                float* __restrict__ zp_part) {
  int b = blockIdx.y;
  int rx = blockIdx.x;
  int r0 = rx * 64;
  int t = threadIdx.x, lane = t & 63, w = t >> 6;
  float ge[8], bee[8];
  #pragma unroll
  for (int e = 0; e < 8; ++e) { ge[e] = g[lane * 8 + e]; bee[e] = be[lane * 8 + e]; }
  float acc[8] = {0, 0, 0, 0, 0, 0, 0, 0};
  for (int rr = 0; rr < 16; ++rr) {
    int row = r0 + w * 16 + rr;
    const bf16* p = H2 + ((size_t)b * N_ + row) * D_ + lane * 8;
    bf16x8 hv = *(const bf16x8*)p;
    float x[8];
    float s = 0.f;
    #pragma unroll
    for (int e = 0; e < 8; ++e) { x[e] = (float)hv[e]; s += x[e]; }
    #pragma unroll
    for (int off = 32; off; off >>= 1) s += __shfl_xor(s, off);
    float mu = s * (1.f / 512.f);
    float ss = 0.f;
    #pragma unroll
    for (int e = 0; e < 8; ++e) { float d = x[e] - mu; ss += d * d; }
    #pragma unroll
    for (int off = 32; off; off >>= 1) ss += __shfl_xor(ss, off);
    float rs = rsqrtf(ss * (1.f / 512.f) + LN_EPS);
    #pragma unroll
    for (int e = 0; e < 8; ++e) acc[e] += (x[e] - mu) * rs * ge[e] + bee[e];
  }
  __shared__ float part[4][512];
  #pragma unroll
  for (int e = 0; e < 8; ++e) part[w][lane * 8 + e] = acc[e];
  __syncthreads();
  #pragma unroll
  for (int k = 0; k < 2; ++k) {
    int d = t + k * 256;
    float s4 = part[0][d] + part[1][d] + part[2][d] + part[3][d];
    zp_part[((size_t)rx * B_ + b) * D_ + d] = s4;
  }
}

// ---------------- classifier head (reduces zp partials) ----------------
__global__ __launch_bounds__(128) void k_cls(
    const float* __restrict__ zp_part,
    const float* __restrict__ Wc1, const float* __restrict__ bc1,
    const float* __restrict__ g1, const float* __restrict__ t1,
    const float* __restrict__ Wc2, const float* __restrict__ bc2,
    const float* __restrict__ g2, const float* __restrict__ t2,
    const float* __restrict__ Wc3, const float* __restrict__ bc3,
    float* __restrict__ out) {
  __shared__ float z[512];
  __shared__ float c1s[128];
  __shared__ float c2s[64];
  __shared__ float red[128];
  int b = blockIdx.x, t = threadIdx.x;
  #pragma unroll
  for (int k = 0; k < 4; ++k) {
    int d = t + k * 128;
    float s = 0.f;
    #pragma unroll
    for (int rx = 0; rx < 16; ++rx)
      s += zp_part[((size_t)rx * B_ + b) * D_ + d];
    float v = s * (1.f / 1024.f);
    z[d] = v;
    out[128 + b * 512 + d] = v;   // z_pooled output region
  }
  __syncthreads();
  float y = bc1[t];
  for (int d = 0; d < 512; ++d) y += z[d] * Wc1[d * 128 + t];
  red[t] = y;
  __syncthreads();
  float mu = 0.f;
  for (int k = 0; k < 128; ++k) mu += red[k];
  mu *= (1.f / 128.f);
  float var = 0.f;
  for (int k = 0; k < 128; ++k) { float dd = red[k] - mu; var += dd * dd; }
  var *= (1.f / 128.f);
  float c = (y - mu) * rsqrtf(var + LN_EPS) * g1[t] + t1[t];
  c1s[t] = c > 0.f ? c : 0.f;
  __syncthreads();
  if (t < 64) {
    float y2 = bc2[t];
    for (int k = 0; k < 128; ++k) y2 += c1s[k] * Wc2[k * 64 + t];
    red[t] = y2;
  }
  __syncthreads();
  if (t < 64) {
    float mu2 = 0.f;
    for (int k = 0; k < 64; ++k) mu2 += red[k];
    mu2 *= (1.f / 64.f);
    float v2 = 0.f;
    for (int k = 0; k < 64; ++k) { float dd = red[k] - mu2; v2 += dd * dd; }
    v2 *= (1.f / 64.f);
    float cc = (red[t] - mu2) * rsqrtf(v2 + LN_EPS) * g2[t] + t2[t];
    c2s[t] = cc > 0.f ? cc : 0.f;
  }
  __syncthreads();
  if (t < 4) {
    float y3 = bc3[t];
    for (int k = 0; k < 64; ++k) y3 += c2s[k] * Wc3[k * 4 + t];
    out[b * 4 + t] = y3;
  }
}

extern "C" void kernel_launch(void* const* d_in, const int* in_sizes, int n_in,
                              void* d_out, int out_size, void* d_ws, size_t ws_size,
                              hipStream_t stream) {
  const float* A   = (const float*)d_in[0];
  const float* W1  = (const float*)d_in[1];
  const float* b1  = (const float*)d_in[2];
  const float* W2  = (const float*)d_in[3];
  const float* b2  = (const float*)d_in[4];
  const float* lng = (const float*)d_in[5];
  const float* lnb = (const float*)d_in[6];
  const float* Wc1 = (const float*)d_in[7];
  const float* bc1 = (const float*)d_in[8];
  const float* g1  = (const float*)d_in[9];
  const float* t1  = (const float*)d_in[10];
  const float* Wc2 = (const float*)d_in[11];
  const float* bc2 = (const float*)d_in[12];
  const float* g2  = (const float*)d_in[13];
  const float* t2  = (const float*)d_in[14];
  const float* Wc3 = (const float*)d_in[15];
  const float* bc3 = (const float*)d_in[16];
  float* out = (float*)d_out;

  char* ws = (char*)d_ws;
  size_t off = 0;
  auto alloc = [&](size_t bytes) {
    char* p = ws + off;
    off += (bytes + 255) & ~(size_t)255;
    return p;
  };
  float* deg_part = (float*)alloc((size_t)16 * B_ * N_ * 4);  // 2 MB partials
  float* zp_part  = (float*)alloc((size_t)16 * B_ * D_ * 4);  // 1 MB partials
  bf16* Anbf  = (bf16*)alloc((size_t)B_ * N_ * N_ * 2);       // 64 MB
  bf16* W1t   = (bf16*)alloc((size_t)D_ * N_ * 2);            // [512 x 1024]
  bf16* W2t   = (bf16*)alloc((size_t)D_ * D_ * 2);            // [512 x 512]
  bf16* T12t  = (bf16*)alloc((size_t)B_ * D_ * N_ * 2);       // T1t then T2t
  bf16* H1    = (bf16*)alloc((size_t)B_ * N_ * D_ * 2);       // [b][1024][512]
  bf16* Abf   = (bf16*)alloc((size_t)B_ * N_ * N_ * 2);       // later reused as H2
  bf16* H2    = Abf;                                           // Abf dead after GEMM1

  // no memset needed: deg_part and zp_part are fully written before read

  k_pre<<<704, 256, 0, stream>>>(A, deg_part, Abf, W1, W1t, W2, W2t);
  k_build<<<dim3(16, 16, B_), 256, 0, stream>>>(Abf, deg_part, Anbf);

  // G1: T1t[512,1024] = W1t @ Abf^T   (T1 = A @ W1, transposed)
  k_gemm<false, false><<<dim3(4, 4, B_), 256, 0, stream>>>(
      W1t, 0, Abf, (size_t)N_ * N_, T12t, (size_t)D_ * N_, nullptr, N_, N_);
  // G2: H1[1024,512] = relu(An @ T1t^T + b1)
  k_gemm<true, true><<<dim3(2, 8, B_), 256, 0, stream>>>(
      Anbf, (size_t)N_ * N_, T12t, (size_t)D_ * N_, H1, (size_t)N_ * D_, b1, D_, N_);
  // G3: T2t[512,1024] = W2t @ H1^T
  k_gemm<false, false><<<dim3(4, 4, B_), 256, 0, stream>>>(
      W2t, 0, H1, (size_t)N_ * D_, T12t, (size_t)D_ * N_, nullptr, N_, D_);
  // G4: H2[1024,512] = An @ T2t^T + b2
  k_gemm<true, false><<<dim3(2, 8, B_), 256, 0, stream>>>(
      Anbf, (size_t)N_ * N_, T12t, (size_t)D_ * N_, H2, (size_t)N_ * D_, b2, D_, N_);

  k_lnpool<<<dim3(16, B_), 256, 0, stream>>>(H2, lng, lnb, zp_part);
  k_cls<<<B_, 128, 0, stream>>>(zp_part, Wc1, bc1, g1, t1, Wc2, bc2, g2, t2,
                                Wc3, bc3, out);
}

// Round 13
// 416.315 us; speedup vs baseline: 1.0367x; 1.0050x over previous
//
#include <hip/hip_runtime.h>
#include <hip/hip_bf16.h>

#define B_ 32
#define N_ 1024
#define D_ 512
#define LN_EPS 1e-5f

using bf16 = __bf16;
using bf16x4 = __attribute__((ext_vector_type(4))) __bf16;
using bf16x8 = __attribute__((ext_vector_type(8))) __bf16;
using floatx4 = __attribute__((ext_vector_type(4))) float;

__device__ __forceinline__ void gld16(const bf16* gp, bf16* lp) {
  __builtin_amdgcn_global_load_lds(
      (const __attribute__((address_space(1))) void*)gp,
      (__attribute__((address_space(3))) void*)lp, 16, 0, 0);
}

// ---- fused pre-pass, no atomics / no memset (r11) ----
__global__ __launch_bounds__(256) void k_pre(const float* __restrict__ A,
                                             float* __restrict__ deg_part,
                                             bf16* __restrict__ Abf,
                                             const float* __restrict__ W1,
                                             bf16* __restrict__ W1t,
                                             const float* __restrict__ W2,
                                             bf16* __restrict__ W2t) {
  int blk = blockIdx.x;
  int t = threadIdx.x;
  if (blk < 512) {
    int b = blk >> 4;
    int rc = blk & 15;
    int r0 = rc * 64;
    const float* p = A + (size_t)b * N_ * N_ + (size_t)r0 * N_ + t * 4;
    bf16* op = Abf + (size_t)b * N_ * N_ + (size_t)r0 * N_ + t * 4;
    float4 acc = {0.f, 0.f, 0.f, 0.f};
    #pragma unroll 4
    for (int i = 0; i < 64; ++i) {
      float4 v = *(const float4*)(p + (size_t)i * N_);
      acc.x += v.x; acc.y += v.y; acc.z += v.z; acc.w += v.w;
      bf16x4 o = {(bf16)v.x, (bf16)v.y, (bf16)v.z, (bf16)v.w};
      *(bf16x4*)(op + (size_t)i * N_) = o;
    }
    *(float4*)(deg_part + ((size_t)rc * B_ + b) * N_ + t * 4) = acc;
  } else {
    __shared__ float tile[64][65];
    blk -= 512;
    const float* in; bf16* outp; int R, C, c0, r0;
    if (blk < 128) {
      in = W1; outp = W1t; R = N_; C = D_;
      c0 = (blk & 7) * 64; r0 = (blk >> 3) * 64;
    } else {
      blk -= 128;
      in = W2; outp = W2t; R = D_; C = D_;
      c0 = (blk & 7) * 64; r0 = (blk >> 3) * 64;
    }
    #pragma unroll
    for (int cc = 0; cc < 4; ++cc) {
      int idx = cc * 256 + t;
      int r = idx >> 4, c4 = (idx & 15) << 2;
      const float4 v = *(const float4*)(in + (size_t)(r0 + r) * C + c0 + c4);
      tile[r][c4 + 0] = v.x; tile[r][c4 + 1] = v.y;
      tile[r][c4 + 2] = v.z; tile[r][c4 + 3] = v.w;
    }
    __syncthreads();
    #pragma unroll
    for (int cc = 0; cc < 4; ++cc) {
      int idx = cc * 256 + t;
      int c = idx >> 4, r4 = (idx & 15) << 2;
      bf16* dst = outp + (size_t)(c0 + c) * R + r0 + r4;
      #pragma unroll
      for (int e = 0; e < 4; ++e) dst[e] = (bf16)tile[r4 + e][c];
    }
  }
}

// ---- fused dispatch: G1 GEMM (blocks 0..511) || k_build (blocks 512..8703) ----
// Independent work: G1 = W1t @ Abf^T (reads Abf, W1t); build = An from
// Abf+deg (writes Anbf). Compute-bound G1 blocks seed the CUs; memory-bound
// build blocks fill remaining slots -> overlap without multi-stream.
__global__ __launch_bounds__(256, 2) void k_g1_build(
    const bf16* __restrict__ W1t, const bf16* __restrict__ Abf,
    bf16* __restrict__ T12t, const float* __restrict__ deg_part,
    bf16* __restrict__ Anbf) {
  __shared__ __align__(16) char smraw[49152];   // 48KB union
  int blk = blockIdx.x;
  int t = threadIdx.x;
  if (blk < 512) {
    // ================= G1: 128x256 MFMA GEMM (r0 structure) =================
    bf16* smem = (bf16*)smraw;
    bf16* sA = smem;           // 128*64
    bf16* sB = smem + 8192;    // 256*64
    const int Nn = N_, K = N_;
    // XCD swizzle (nxy=16): identical math to the dim3(4,4,32) launch.
    int L = blk;
    int b = (L & 7) + 8 * (L >> 7);
    int inner = (L >> 3) & 15;
    int n0 = (inner & 3) * 256;
    int m0 = (inner >> 2) * 128;

    const bf16* A = W1t;                      // strideA = 0 (shared weights)
    const bf16* Bt = Abf + (size_t)b * N_ * N_;
    int lane = t & 63, wid = t >> 6;
    int wm = (wid >> 1) * 64, wn = (wid & 1) * 128;
    int l16 = lane & 15, q = lane >> 4;
    int rowoff = lane >> 3;
    int schunk = (lane & 7) ^ rowoff;
    const bf16* agp = A + (size_t)(m0 + wid * 32 + rowoff) * K + schunk * 8;
    const bf16* bgp = Bt + (size_t)(n0 + wid * 64 + rowoff) * K + schunk * 8;
    bf16* alp = &sA[wid * 2048 + lane * 8];
    bf16* blp = &sB[wid * 4096 + lane * 8];
    int xorb = l16 & 7;

    floatx4 acc[4][8];
    #pragma unroll
    for (int i = 0; i < 4; ++i)
      #pragma unroll
      for (int j = 0; j < 8; ++j) acc[i][j] = (floatx4){0.f, 0.f, 0.f, 0.f};

    for (int kt = 0; kt < K; kt += 64) {
      #pragma unroll
      for (int s = 0; s < 4; ++s)
        gld16(agp + (size_t)s * 8 * K + kt, alp + s * 512);
      #pragma unroll
      for (int s = 0; s < 8; ++s)
        gld16(bgp + (size_t)s * 8 * K + kt, blp + s * 512);
      __syncthreads();
      #pragma unroll
      for (int h = 0; h < 2; ++h) {
        int cko = ((q + 4 * h) ^ xorb) * 8;
        bf16x8 af[4], bfr[8];
        #pragma unroll
        for (int mt = 0; mt < 4; ++mt)
          af[mt] = *(const bf16x8*)(&sA[(wm + mt * 16 + l16) * 64 + cko]);
        #pragma unroll
        for (int nt = 0; nt < 8; ++nt)
          bfr[nt] = *(const bf16x8*)(&sB[(wn + nt * 16 + l16) * 64 + cko]);
        #pragma unroll
        for (int mt = 0; mt < 4; ++mt)
          #pragma unroll
          for (int nt = 0; nt < 8; ++nt)
            acc[mt][nt] = __builtin_amdgcn_mfma_f32_16x16x32_bf16(
                af[mt], bfr[nt], acc[mt][nt], 0, 0, 0);
      }
      __syncthreads();
    }

    bf16* C = T12t + (size_t)b * D_ * N_;
    #pragma unroll
    for (int h = 0; h < 2; ++h) {
      if ((wid >> 1) == h) {
        #pragma unroll
        for (int mt = 0; mt < 4; ++mt)
          #pragma unroll
          for (int nt = 0; nt < 8; ++nt)
            #pragma unroll
            for (int r = 0; r < 4; ++r) {
              float v = acc[mt][nt][r];
              int col = wn + nt * 16 + l16;
              smem[(mt * 16 + q * 4 + r) * 264 + col] = (bf16)v;
            }
      }
      __syncthreads();
      #pragma unroll
      for (int i = 0; i < 8; ++i) {
        int idx = i * 256 + t;
        int row = idx >> 5;
        int c8 = (idx & 31) << 3;
        bf16x8 vv = *(const bf16x8*)(smem + row * 264 + c8);
        *(bf16x8*)(C + (size_t)(m0 + h * 64 + row) * Nn + n0 + c8) = vv;
      }
      if (h == 0) __syncthreads();
    }
  } else {
    // ================= k_build: Anbf tile transpose+scale =================
    float* tile = (float*)smraw;                       // [64][65]
    float* disI = (float*)(smraw + 16640);             // 64 floats
    float* disJ = disI + 64;
    int j2 = blk - 512;                                // 0..8191
    int b = j2 >> 8;
    int i0 = ((j2 >> 4) & 15) * 64;
    int j0 = (j2 & 15) * 64;
    const bf16* Ab = Abf + (size_t)b * N_ * N_;
    bf16* Anb = Anbf + (size_t)b * N_ * N_;
    if (t < 64) {
      float v = 0.f;
      #pragma unroll
      for (int rc = 0; rc < 16; ++rc)
        v += deg_part[((size_t)rc * B_ + b) * N_ + i0 + t];
      disI[t] = v > 0.f ? rsqrtf(v) : 0.f;
    } else if (t < 128) {
      float v = 0.f;
      #pragma unroll
      for (int rc = 0; rc < 16; ++rc)
        v += deg_part[((size_t)rc * B_ + b) * N_ + j0 + (t - 64)];
      disJ[t - 64] = v > 0.f ? rsqrtf(v) : 0.f;
    }
    #pragma unroll
    for (int cc = 0; cc < 2; ++cc) {
      int idx = cc * 256 + t;
      int r = idx >> 3;
      int c8 = (idx & 7) << 3;
      bf16x8 v = *(const bf16x8*)(Ab + (size_t)(j0 + r) * N_ + i0 + c8);
      #pragma unroll
      for (int e = 0; e < 8; ++e) tile[r * 65 + c8 + e] = (float)v[e];
    }
    __syncthreads();
    #pragma unroll
    for (int cc = 0; cc < 2; ++cc) {
      int idx = cc * 256 + t;
      int ii = idx >> 3;
      int jj8 = (idx & 7) << 3;
      float di = disI[ii];
      bf16x8 o;
      #pragma unroll
      for (int e = 0; e < 8; ++e)
        o[e] = (bf16)(tile[(jj8 + e) * 65 + ii] * di * disJ[jj8 + e]);
      *(bf16x8*)(Anb + (size_t)(i0 + ii) * N_ + j0 + jj8) = o;
    }
  }
}

// --------- MFMA GEMM: C[M,Nn] = A[M,K] @ Bt[Nn,K]^T (r0 structure) ----------
// 128x256 block tile, 4 waves each 64x128, BK=64, two-barrier K-loop,
// XOR-swizzled LDS, XCD-aware block swizzle, 48KB LDS, coalesced epilogue.
template <bool BIAS, bool RELU>
__global__ __launch_bounds__(256, 2) void k_gemm(
    const bf16* __restrict__ Abase, size_t strideA,
    const bf16* __restrict__ Btbase, size_t strideBt,
    bf16* __restrict__ Cbase, size_t strideC,
    const float* __restrict__ bias, int Nn, int K) {
  __shared__ __align__(16) bf16 smem[24576];   // 48KB: sA | sB
  bf16* sA = smem;           // 128*64
  bf16* sB = smem + 8192;    // 256*64
  int nxy = gridDim.x * gridDim.y;
  int L = blockIdx.z * nxy + blockIdx.y * gridDim.x + blockIdx.x;
  int b = (L & 7) + 8 * (L / (nxy * 8));
  int inner = (L >> 3) % nxy;
  int n0 = (inner % gridDim.x) * 256;
  int m0 = (inner / gridDim.x) * 128;

  const bf16* A = Abase + (size_t)b * strideA;
  const bf16* Bt = Btbase + (size_t)b * strideBt;
  int t = threadIdx.x;
  int lane = t & 63, wid = t >> 6;
  int wm = (wid >> 1) * 64, wn = (wid & 1) * 128;
  int l16 = lane & 15, q = lane >> 4;
  int rowoff = lane >> 3;
  int schunk = (lane & 7) ^ rowoff;
  const bf16* agp = A + (size_t)(m0 + wid * 32 + rowoff) * K + schunk * 8;
  const bf16* bgp = Bt + (size_t)(n0 + wid * 64 + rowoff) * K + schunk * 8;
  bf16* alp = &sA[wid * 2048 + lane * 8];
  bf16* blp = &sB[wid * 4096 + lane * 8];
  int xorb = l16 & 7;

  floatx4 acc[4][8];
  #pragma unroll
  for (int i = 0; i < 4; ++i)
    #pragma unroll
    for (int j = 0; j < 8; ++j) acc[i][j] = (floatx4){0.f, 0.f, 0.f, 0.f};

  for (int kt = 0; kt < K; kt += 64) {
    #pragma unroll
    for (int s = 0; s < 4; ++s)
      gld16(agp + (size_t)s * 8 * K + kt, alp + s * 512);
    #pragma unroll
    for (int s = 0; s < 8; ++s)
      gld16(bgp + (size_t)s * 8 * K + kt, blp + s * 512);
    __syncthreads();
    #pragma unroll
    for (int h = 0; h < 2; ++h) {
      int cko = ((q + 4 * h) ^ xorb) * 8;
      bf16x8 af[4], bfr[8];
      #pragma unroll
      for (int mt = 0; mt < 4; ++mt)
        af[mt] = *(const bf16x8*)(&sA[(wm + mt * 16 + l16) * 64 + cko]);
      #pragma unroll
      for (int nt = 0; nt < 8; ++nt)
        bfr[nt] = *(const bf16x8*)(&sB[(wn + nt * 16 + l16) * 64 + cko]);
      #pragma unroll
      for (int mt = 0; mt < 4; ++mt)
        #pragma unroll
        for (int nt = 0; nt < 8; ++nt)
          acc[mt][nt] = __builtin_amdgcn_mfma_f32_16x16x32_bf16(
              af[mt], bfr[nt], acc[mt][nt], 0, 0, 0);
    }
    __syncthreads();
  }

  bf16* C = Cbase + (size_t)b * strideC;
  #pragma unroll
  for (int h = 0; h < 2; ++h) {
    if ((wid >> 1) == h) {
      #pragma unroll
      for (int mt = 0; mt < 4; ++mt)
        #pragma unroll
        for (int nt = 0; nt < 8; ++nt)
          #pragma unroll
          for (int r = 0; r < 4; ++r) {
            float v = acc[mt][nt][r];
            int col = wn + nt * 16 + l16;
            if (BIAS) v += bias[n0 + col];
            if (RELU) v = v > 0.f ? v : 0.f;
            smem[(mt * 16 + q * 4 + r) * 264 + col] = (bf16)v;
          }
    }
    __syncthreads();
    #pragma unroll
    for (int i = 0; i < 8; ++i) {
      int idx = i * 256 + t;
      int row = idx >> 5;
      int c8 = (idx & 31) << 3;
      bf16x8 vv = *(const bf16x8*)(smem + row * 264 + c8);
      *(bf16x8*)(C + (size_t)(m0 + h * 64 + row) * Nn + n0 + c8) = vv;
    }
    if (h == 0) __syncthreads();
  }
}

// ------- LayerNorm over D + mean-pool over N: per-block partials (no atomics) -------
__global__ __launch_bounds__(256) void k_lnpool(const bf16* __restrict__ H2,
                                                const float* __restrict__ g,
                                                const float* __restrict__ be,
                                                float* __restrict__ zp_part) {
  int b = blockIdx.y;
  int rx = blockIdx.x;
  int r0 = rx * 64;
  int t = threadIdx.x, lane = t & 63, w = t >> 6;
  float ge[8], bee[8];
  #pragma unroll
  for (int e = 0; e < 8; ++e) { ge[e] = g[lane * 8 + e]; bee[e] = be[lane * 8 + e]; }
  float acc[8] = {0, 0, 0, 0, 0, 0, 0, 0};
  for (int rr = 0; rr < 16; ++rr) {
    int row = r0 + w * 16 + rr;
    const bf16* p = H2 + ((size_t)b * N_ + row) * D_ + lane * 8;
    bf16x8 hv = *(const bf16x8*)p;
    float x[8];
    float s = 0.f;
    #pragma unroll
    for (int e = 0; e < 8; ++e) { x[e] = (float)hv[e]; s += x[e]; }
    #pragma unroll
    for (int off = 32; off; off >>= 1) s += __shfl_xor(s, off);
    float mu = s * (1.f / 512.f);
    float ss = 0.f;
    #pragma unroll
    for (int e = 0; e < 8; ++e) { float d = x[e] - mu; ss += d * d; }
    #pragma unroll
    for (int off = 32; off; off >>= 1) ss += __shfl_xor(ss, off);
    float rs = rsqrtf(ss * (1.f / 512.f) + LN_EPS);
    #pragma unroll
    for (int e = 0; e < 8; ++e) acc[e] += (x[e] - mu) * rs * ge[e] + bee[e];
  }
  __shared__ float part[4][512];
  #pragma unroll
  for (int e = 0; e < 8; ++e) part[w][lane * 8 + e] = acc[e];
  __syncthreads();
  #pragma unroll
  for (int k = 0; k < 2; ++k) {
    int d = t + k * 256;
    float s4 = part[0][d] + part[1][d] + part[2][d] + part[3][d];
    zp_part[((size_t)rx * B_ + b) * D_ + d] = s4;
  }
}

// ---------------- classifier head (reduces zp partials) ----------------
__global__ __launch_bounds__(128) void k_cls(
    const float* __restrict__ zp_part,
    const float* __restrict__ Wc1, const float* __restrict__ bc1,
    const float* __restrict__ g1, const float* __restrict__ t1,
    const float* __restrict__ Wc2, const float* __restrict__ bc2,
    const float* __restrict__ g2, const float* __restrict__ t2,
    const float* __restrict__ Wc3, const float* __restrict__ bc3,
    float* __restrict__ out) {
  __shared__ float z[512];
  __shared__ float c1s[128];
  __shared__ float c2s[64];
  __shared__ float red[128];
  int b = blockIdx.x, t = threadIdx.x;
  #pragma unroll
  for (int k = 0; k < 4; ++k) {
    int d = t + k * 128;
    float s = 0.f;
    #pragma unroll
    for (int rx = 0; rx < 16; ++rx)
      s += zp_part[((size_t)rx * B_ + b) * D_ + d];
    float v = s * (1.f / 1024.f);
    z[d] = v;
    out[128 + b * 512 + d] = v;   // z_pooled output region
  }
  __syncthreads();
  float y = bc1[t];
  for (int d = 0; d < 512; ++d) y += z[d] * Wc1[d * 128 + t];
  red[t] = y;
  __syncthreads();
  float mu = 0.f;
  for (int k = 0; k < 128; ++k) mu += red[k];
  mu *= (1.f / 128.f);
  float var = 0.f;
  for (int k = 0; k < 128; ++k) { float dd = red[k] - mu; var += dd * dd; }
  var *= (1.f / 128.f);
  float c = (y - mu) * rsqrtf(var + LN_EPS) * g1[t] + t1[t];
  c1s[t] = c > 0.f ? c : 0.f;
  __syncthreads();
  if (t < 64) {
    float y2 = bc2[t];
    for (int k = 0; k < 128; ++k) y2 += c1s[k] * Wc2[k * 64 + t];
    red[t] = y2;
  }
  __syncthreads();
  if (t < 64) {
    float mu2 = 0.f;
    for (int k = 0; k < 64; ++k) mu2 += red[k];
    mu2 *= (1.f / 64.f);
    float v2 = 0.f;
    for (int k = 0; k < 64; ++k) { float dd = red[k] - mu2; v2 += dd * dd; }
    v2 *= (1.f / 64.f);
    float cc = (red[t] - mu2) * rsqrtf(v2 + LN_EPS) * g2[t] + t2[t];
    c2s[t] = cc > 0.f ? cc : 0.f;
  }
  __syncthreads();
  if (t < 4) {
    float y3 = bc3[t];
    for (int k = 0; k < 64; ++k) y3 += c2s[k] * Wc3[k * 4 + t];
    out[b * 4 + t] = y3;
  }
}

extern "C" void kernel_launch(void* const* d_in, const int* in_sizes, int n_in,
                              void* d_out, int out_size, void* d_ws, size_t ws_size,
                              hipStream_t stream) {
  const float* A   = (const float*)d_in[0];
  const float* W1  = (const float*)d_in[1];
  const float* b1  = (const float*)d_in[2];
  const float* W2  = (const float*)d_in[3];
  const float* b2  = (const float*)d_in[4];
  const float* lng = (const float*)d_in[5];
  const float* lnb = (const float*)d_in[6];
  const float* Wc1 = (const float*)d_in[7];
  const float* bc1 = (const float*)d_in[8];
  const float* g1  = (const float*)d_in[9];
  const float* t1  = (const float*)d_in[10];
  const float* Wc2 = (const float*)d_in[11];
  const float* bc2 = (const float*)d_in[12];
  const float* g2  = (const float*)d_in[13];
  const float* t2  = (const float*)d_in[14];
  const float* Wc3 = (const float*)d_in[15];
  const float* bc3 = (const float*)d_in[16];
  float* out = (float*)d_out;

  char* ws = (char*)d_ws;
  size_t off = 0;
  auto alloc = [&](size_t bytes) {
    char* p = ws + off;
    off += (bytes + 255) & ~(size_t)255;
    return p;
  };
  float* deg_part = (float*)alloc((size_t)16 * B_ * N_ * 4);  // 2 MB partials
  float* zp_part  = (float*)alloc((size_t)16 * B_ * D_ * 4);  // 1 MB partials
  bf16* Anbf  = (bf16*)alloc((size_t)B_ * N_ * N_ * 2);       // 64 MB
  bf16* W1t   = (bf16*)alloc((size_t)D_ * N_ * 2);            // [512 x 1024]
  bf16* W2t   = (bf16*)alloc((size_t)D_ * D_ * 2);            // [512 x 512]
  bf16* T12t  = (bf16*)alloc((size_t)B_ * D_ * N_ * 2);       // T1t then T2t
  bf16* H1    = (bf16*)alloc((size_t)B_ * N_ * D_ * 2);       // [b][1024][512]
  bf16* Abf   = (bf16*)alloc((size_t)B_ * N_ * N_ * 2);       // later reused as H2
  bf16* H2    = Abf;                                           // Abf dead after GEMM1

  // no memset needed: deg_part and zp_part are fully written before read

  k_pre<<<704, 256, 0, stream>>>(A, deg_part, Abf, W1, W1t, W2, W2t);

  // G1 (blocks 0..511) overlapped with k_build (blocks 512..8703):
  // independent work, one dispatch.
  k_g1_build<<<8704, 256, 0, stream>>>(W1t, Abf, T12t, deg_part, Anbf);

  // G2: H1[1024,512] = relu(An @ T1t^T + b1)
  k_gemm<true, true><<<dim3(2, 8, B_), 256, 0, stream>>>(
      Anbf, (size_t)N_ * N_, T12t, (size_t)D_ * N_, H1, (size_t)N_ * D_, b1, D_, N_);
  // G3: T2t[512,1024] = W2t @ H1^T
  k_gemm<false, false><<<dim3(4, 4, B_), 256, 0, stream>>>(
      W2t, 0, H1, (size_t)N_ * D_, T12t, (size_t)D_ * N_, nullptr, N_, D_);
  // G4: H2[1024,512] = An @ T2t^T + b2
  k_gemm<true, false><<<dim3(2, 8, B_), 256, 0, stream>>>(
      Anbf, (size_t)N_ * N_, T12t, (size_t)D_ * N_, H2, (size_t)N_ * D_, b2, D_, N_);

  k_lnpool<<<dim3(16, B_), 256, 0, stream>>>(H2, lng, lnb, zp_part);
  k_cls<<<B_, 128, 0, stream>>>(zp_part, Wc1, bc1, g1, t1, Wc2, bc2, g2, t2,
                                Wc3, bc3, out);
}